// Round 1
// baseline (5820.710 us; speedup 1.0000x reference)
//
#include <hip/hip_runtime.h>

#define NN 100000
#define NE 1600000
#define D 128
#define LEAKY 0.01f
#define BNEPS 1e-5f

// ---------------- degree + norm ----------------

__global__ void deg_kernel(const int* __restrict__ src, const int* __restrict__ dst,
                           int* __restrict__ deg) {
    int e = blockIdx.x * blockDim.x + threadIdx.x;
    if (e < NE) {
        atomicAdd(&deg[src[e]], 1);        // out-degree
        atomicAdd(&deg[NN + dst[e]], 1);   // in-degree
    }
}

__global__ void norm_kernel(const int* __restrict__ deg, float* __restrict__ norm) {
    int i = blockIdx.x * blockDim.x + threadIdx.x;
    if (i < NN) {
        // +1 for the self-loop; max(deg,1) is then a no-op
        norm[i]      = rsqrtf((float)(deg[i] + 1));
        norm[NN + i] = rsqrtf((float)(deg[NN + i] + 1));
    }
}

// ---------------- agg init = self-loop contribution ----------------

__global__ void init_agg0(const float* __restrict__ x, const float* __restrict__ norm_s,
                          float* __restrict__ agg) {
    int t = blockIdx.x * blockDim.x + threadIdx.x;   // NN*32 threads
    int i = t >> 5;
    if (i >= NN) return;
    int c = (t & 31) << 2;
    float ns = norm_s[i];
    float4 v = *(const float4*)(x + (size_t)i * D + c);
    v.x *= ns; v.y *= ns; v.z *= ns; v.w *= ns;
    *(float4*)(agg + (size_t)i * D + c) = v;
}

// ---------------- edge scatter-add (SpMM) ----------------
// 32 threads per edge, float4 per thread, 4 fp32 atomics per thread.

template<bool SCALE_SRC>
__global__ void edge_agg(const int* __restrict__ src, const int* __restrict__ dst,
                         const float* __restrict__ h, const float* __restrict__ norm_s,
                         float* __restrict__ agg) {
    int t = blockIdx.x * blockDim.x + threadIdx.x;   // NE*32 threads
    int e = t >> 5;
    if (e >= NE) return;
    int c = (t & 31) << 2;
    int s = src[e], d = dst[e];
    float4 v = *(const float4*)(h + (size_t)s * D + c);
    if (SCALE_SRC) {
        float ns = norm_s[s];
        v.x *= ns; v.y *= ns; v.z *= ns; v.w *= ns;
    }
    float* p = agg + (size_t)d * D + c;
    atomicAdd(p + 0, v.x);
    atomicAdd(p + 1, v.y);
    atomicAdd(p + 2, v.z);
    atomicAdd(p + 3, v.w);
}

// ---------------- fused GEMM (+ norm_dst, bias, BN, leaky, norm_src) ----------------
// W (128x128 f32, 64 KB) staged in LDS. One wave handles 4 rows, 2 output
// channels per lane (j and j+64). W[k][j] reads hit bank j%32 -> 2-way
// aliasing across 64 lanes = free. norm_dst folded after accumulation.

template<bool LAYER0>
__global__ __launch_bounds__(256, 2) void gemm_kernel(
    const float* __restrict__ agg, const float* __restrict__ W,
    const float* __restrict__ bias,
    const float* __restrict__ norm_s, const float* __restrict__ norm_d,
    const float* __restrict__ gamma, const float* __restrict__ beta,
    const float* __restrict__ rmean, const float* __restrict__ rvar,
    float* __restrict__ out0, float* out1)
{
    __shared__ float Wl[D * D];
    for (int idx = threadIdx.x; idx < D * D / 4; idx += 256)
        ((float4*)Wl)[idx] = ((const float4*)W)[idx];
    __syncthreads();

    const int wave = threadIdx.x >> 6;
    const int lane = threadIdx.x & 63;
    const int j0 = lane, j1 = lane + 64;

    const float b0 = bias[j0], b1v = bias[j1];
    float s0 = 0.f, sh0 = 0.f, s1 = 0.f, sh1 = 0.f;
    if (LAYER0) {
        s0  = gamma[j0] * rsqrtf(rvar[j0] + BNEPS);
        sh0 = beta[j0] - rmean[j0] * s0;
        s1  = gamma[j1] * rsqrtf(rvar[j1] + BNEPS);
        sh1 = beta[j1] - rmean[j1] * s1;
    }

    const int ROWS = 4;
    const int wave_id = blockIdx.x * 4 + wave;
    const int nwaves = gridDim.x * 4;
    for (int base = wave_id * ROWS; base < NN; base += nwaves * ROWS) {
        float acc[ROWS][2] = {};
        const float* rp = agg + (size_t)base * D;
        #pragma unroll 4
        for (int k = 0; k < D; k += 4) {
            float vv[ROWS][4];
            *(float4*)&vv[0][0] = *(const float4*)(rp + 0 * D + k);
            *(float4*)&vv[1][0] = *(const float4*)(rp + 1 * D + k);
            *(float4*)&vv[2][0] = *(const float4*)(rp + 2 * D + k);
            *(float4*)&vv[3][0] = *(const float4*)(rp + 3 * D + k);
            #pragma unroll
            for (int kk = 0; kk < 4; ++kk) {
                float w0 = Wl[(k + kk) * D + j0];
                float w1 = Wl[(k + kk) * D + j1];
                #pragma unroll
                for (int r = 0; r < ROWS; ++r) {
                    acc[r][0] = fmaf(vv[r][kk], w0, acc[r][0]);
                    acc[r][1] = fmaf(vv[r][kk], w1, acc[r][1]);
                }
            }
        }
        #pragma unroll
        for (int r = 0; r < ROWS; ++r) {
            int row = base + r;
            float nd = norm_d[row];
            float o0 = acc[r][0] * nd + b0;
            float o1 = acc[r][1] * nd + b1v;
            if (LAYER0) {
                o0 = o0 * s0 + sh0;
                o1 = o1 * s1 + sh1;
                o0 = o0 > 0.f ? o0 : LEAKY * o0;
                o1 = o1 > 0.f ? o1 : LEAKY * o1;
                float ns = norm_s[row];
                o0 *= ns; o1 *= ns;
                out1[(size_t)row * D + j0] = o0;
                out1[(size_t)row * D + j1] = o1;
            }
            out0[(size_t)row * D + j0] = o0;
            out0[(size_t)row * D + j1] = o1;
        }
    }
}

// ---------------- launch ----------------

extern "C" void kernel_launch(void* const* d_in, const int* in_sizes, int n_in,
                              void* d_out, int out_size, void* d_ws, size_t ws_size,
                              hipStream_t stream) {
    const float* x     = (const float*)d_in[0];
    const int*   src   = (const int*)d_in[1];
    const int*   dst   = (const int*)d_in[2];
    const float* W1    = (const float*)d_in[3];
    const float* b1    = (const float*)d_in[4];
    const float* W2    = (const float*)d_in[5];
    const float* b2    = (const float*)d_in[6];
    const float* gamma = (const float*)d_in[7];
    const float* beta  = (const float*)d_in[8];
    const float* rmean = (const float*)d_in[9];
    const float* rvar  = (const float*)d_in[10];
    float* out = (float*)d_out;

    // ws layout: buf1 (N*D f32 aggregator) | deg (2N i32) | norm (2N f32)
    float* buf1   = (float*)d_ws;
    int*   deg    = (int*)(buf1 + (size_t)NN * D);
    float* norm   = (float*)(deg + 2 * NN);
    float* norm_s = norm;
    float* norm_d = norm + NN;

    hipMemsetAsync(deg, 0, 2 * NN * sizeof(int), stream);
    deg_kernel<<<(NE + 255) / 256, 256, 0, stream>>>(src, dst, deg);
    norm_kernel<<<(NN + 255) / 256, 256, 0, stream>>>(deg, norm);

    // layer 0: agg = selfloop + sum_{e} x[src]*norm_s[src]
    init_agg0<<<(NN * 32 + 255) / 256, 256, 0, stream>>>(x, norm_s, buf1);
    edge_agg<true><<<(NE * 32 + 255) / 256, 256, 0, stream>>>(src, dst, x, norm_s, buf1);
    // gemm1: reads buf1, writes hs (= leaky(BN(agg*nd @ W1 + b1)) * ns) into
    // d_out (gather source for layer 1) and buf1 (self-loop init for layer 1)
    gemm_kernel<true><<<512, 256, 0, stream>>>(buf1, W1, b1, norm_s, norm_d,
                                               gamma, beta, rmean, rvar, out, buf1);
    // layer 1
    edge_agg<false><<<(NE * 32 + 255) / 256, 256, 0, stream>>>(src, dst, out, nullptr, buf1);
    gemm_kernel<false><<<512, 256, 0, stream>>>(buf1, W2, b2, norm_s, norm_d,
                                                nullptr, nullptr, nullptr, nullptr, out, nullptr);
}

// Round 2
// 816.933 us; speedup vs baseline: 7.1251x; 7.1251x over previous
//
#include <hip/hip_runtime.h>

#define NN 100000
#define NE 1600000
#define D 128
#define LEAKY 0.01f
#define BNEPS 1e-5f
#define NB 391   // ceil(NN/256)

// ---------------- degree + norm ----------------

__global__ void deg_kernel(const int* __restrict__ src, const int* __restrict__ dst,
                           int* __restrict__ deg) {
    int e = blockIdx.x * blockDim.x + threadIdx.x;
    if (e < NE) {
        atomicAdd(&deg[src[e]], 1);        // out-degree
        atomicAdd(&deg[NN + dst[e]], 1);   // in-degree
    }
}

__global__ void norm_kernel(const int* __restrict__ deg, float* __restrict__ norm) {
    int i = blockIdx.x * blockDim.x + threadIdx.x;
    if (i < NN) {
        // +1 for the self-loop; max(deg,1) is then a no-op
        norm[i]      = rsqrtf((float)(deg[i] + 1));
        norm[NN + i] = rsqrtf((float)(deg[NN + i] + 1));
    }
}

// ---------------- CSR build: reduce -> scan -> rowptr -> scatter ----------------

__global__ void scan1_reduce(const int* __restrict__ deg_in, int* __restrict__ bsum) {
    __shared__ int sm[256];
    int t = threadIdx.x;
    int i = blockIdx.x * 256 + t;
    sm[t] = (i < NN) ? deg_in[i] : 0;
    __syncthreads();
    for (int s = 128; s > 0; s >>= 1) {
        if (t < s) sm[t] += sm[t + s];
        __syncthreads();
    }
    if (t == 0) bsum[blockIdx.x] = sm[0];
}

__global__ void scan2_offsets(const int* __restrict__ bsum, int* __restrict__ boffs) {
    if (threadIdx.x == 0) {
        int run = 0;
        for (int b = 0; b < NB; ++b) { boffs[b] = run; run += bsum[b]; }
    }
}

__global__ void scan3_rowptr(const int* __restrict__ deg_in, const int* __restrict__ boffs,
                             int* __restrict__ row, int* __restrict__ cursor) {
    __shared__ int sm[256];
    int t = threadIdx.x;
    int i = blockIdx.x * 256 + t;
    int v = (i < NN) ? deg_in[i] : 0;
    sm[t] = v;
    __syncthreads();
    // Hillis-Steele inclusive scan
    for (int off = 1; off < 256; off <<= 1) {
        int a = (t >= off) ? sm[t - off] : 0;
        __syncthreads();
        sm[t] += a;
        __syncthreads();
    }
    if (i < NN) {
        int st = boffs[blockIdx.x] + sm[t] - v;   // exclusive
        row[i] = st;
        cursor[i] = st;
        if (i == NN - 1) row[NN] = st + v;
    }
}

__global__ void scatter_kernel(const int* __restrict__ src, const int* __restrict__ dst,
                               int* __restrict__ cursor, int* __restrict__ csr) {
    int e = blockIdx.x * blockDim.x + threadIdx.x;
    if (e < NE) {
        int d = dst[e];
        int pos = atomicAdd(&cursor[d], 1);
        csr[pos] = src[e];
    }
}

// ---------------- CSR gather-aggregate ----------------
// One wave per dst node; lane holds columns 2*lane, 2*lane+1. Each edge is one
// 512 B coalesced row read. Edge ids loaded 64-at-a-time, broadcast by shuffle.
// Accumulator initialized with the self-loop term (no separate init kernel).

template<bool L0>
__global__ __launch_bounds__(256) void csr_agg(
    const int* __restrict__ row, const int* __restrict__ csr,
    const float* __restrict__ h, const float* __restrict__ norm_s,
    float* __restrict__ agg)
{
    int i = blockIdx.x * 4 + (threadIdx.x >> 6);
    if (i >= NN) return;
    int lane = threadIdx.x & 63;
    int c = lane * 2;

    float2 acc;
    {
        float2 v = *(const float2*)(h + (size_t)i * D + c);
        float w = L0 ? norm_s[i] : 1.0f;
        acc.x = v.x * w; acc.y = v.y * w;
    }

    int start = row[i], end = row[i + 1];
    for (int base = start; base < end; base += 64) {
        int n = end - base; if (n > 64) n = 64;
        int sv = csr[base + (lane < n ? lane : 0)];
        float nsv = L0 ? norm_s[sv] : 1.0f;
        int j = 0;
        for (; j + 4 <= n; j += 4) {
            int s0 = __shfl(sv, j), s1 = __shfl(sv, j + 1);
            int s2 = __shfl(sv, j + 2), s3 = __shfl(sv, j + 3);
            float2 v0 = *(const float2*)(h + (size_t)s0 * D + c);
            float2 v1 = *(const float2*)(h + (size_t)s1 * D + c);
            float2 v2 = *(const float2*)(h + (size_t)s2 * D + c);
            float2 v3 = *(const float2*)(h + (size_t)s3 * D + c);
            if (L0) {
                float w0 = __shfl(nsv, j), w1 = __shfl(nsv, j + 1);
                float w2 = __shfl(nsv, j + 2), w3 = __shfl(nsv, j + 3);
                acc.x = fmaf(v0.x, w0, acc.x); acc.y = fmaf(v0.y, w0, acc.y);
                acc.x = fmaf(v1.x, w1, acc.x); acc.y = fmaf(v1.y, w1, acc.y);
                acc.x = fmaf(v2.x, w2, acc.x); acc.y = fmaf(v2.y, w2, acc.y);
                acc.x = fmaf(v3.x, w3, acc.x); acc.y = fmaf(v3.y, w3, acc.y);
            } else {
                acc.x += v0.x + v1.x + v2.x + v3.x;
                acc.y += v0.y + v1.y + v2.y + v3.y;
            }
        }
        for (; j < n; ++j) {
            int s = __shfl(sv, j);
            float2 v = *(const float2*)(h + (size_t)s * D + c);
            float w = L0 ? __shfl(nsv, j) : 1.0f;
            acc.x = fmaf(v.x, w, acc.x);
            acc.y = fmaf(v.y, w, acc.y);
        }
    }
    *(float2*)(agg + (size_t)i * D + c) = acc;
}

// ---------------- fused GEMM (+ norm_dst, bias, BN, leaky, norm_src) ----------------

template<bool LAYER0>
__global__ __launch_bounds__(256, 2) void gemm_kernel(
    const float* __restrict__ agg, const float* __restrict__ W,
    const float* __restrict__ bias,
    const float* __restrict__ norm_s, const float* __restrict__ norm_d,
    const float* __restrict__ gamma, const float* __restrict__ beta,
    const float* __restrict__ rmean, const float* __restrict__ rvar,
    float* __restrict__ out0)
{
    __shared__ float Wl[D * D];
    for (int idx = threadIdx.x; idx < D * D / 4; idx += 256)
        ((float4*)Wl)[idx] = ((const float4*)W)[idx];
    __syncthreads();

    const int wave = threadIdx.x >> 6;
    const int lane = threadIdx.x & 63;
    const int j0 = lane, j1 = lane + 64;

    const float b0 = bias[j0], b1v = bias[j1];
    float s0 = 0.f, sh0 = 0.f, s1 = 0.f, sh1 = 0.f;
    if (LAYER0) {
        s0  = gamma[j0] * rsqrtf(rvar[j0] + BNEPS);
        sh0 = beta[j0] - rmean[j0] * s0;
        s1  = gamma[j1] * rsqrtf(rvar[j1] + BNEPS);
        sh1 = beta[j1] - rmean[j1] * s1;
    }

    const int ROWS = 4;
    const int wave_id = blockIdx.x * 4 + wave;
    const int nwaves = gridDim.x * 4;
    for (int base = wave_id * ROWS; base < NN; base += nwaves * ROWS) {
        float acc[ROWS][2] = {};
        const float* rp = agg + (size_t)base * D;
        #pragma unroll 4
        for (int k = 0; k < D; k += 4) {
            float vv[ROWS][4];
            *(float4*)&vv[0][0] = *(const float4*)(rp + 0 * D + k);
            *(float4*)&vv[1][0] = *(const float4*)(rp + 1 * D + k);
            *(float4*)&vv[2][0] = *(const float4*)(rp + 2 * D + k);
            *(float4*)&vv[3][0] = *(const float4*)(rp + 3 * D + k);
            #pragma unroll
            for (int kk = 0; kk < 4; ++kk) {
                float w0 = Wl[(k + kk) * D + j0];
                float w1 = Wl[(k + kk) * D + j1];
                #pragma unroll
                for (int r = 0; r < ROWS; ++r) {
                    acc[r][0] = fmaf(vv[r][kk], w0, acc[r][0]);
                    acc[r][1] = fmaf(vv[r][kk], w1, acc[r][1]);
                }
            }
        }
        #pragma unroll
        for (int r = 0; r < ROWS; ++r) {
            int row = base + r;
            float nd = norm_d[row];
            float o0 = acc[r][0] * nd + b0;
            float o1 = acc[r][1] * nd + b1v;
            if (LAYER0) {
                o0 = o0 * s0 + sh0;
                o1 = o1 * s1 + sh1;
                o0 = o0 > 0.f ? o0 : LEAKY * o0;
                o1 = o1 > 0.f ? o1 : LEAKY * o1;
                float ns = norm_s[row];
                o0 *= ns; o1 *= ns;
            }
            out0[(size_t)row * D + j0] = o0;
            out0[(size_t)row * D + j1] = o1;
        }
    }
}

// ---------------- launch ----------------

extern "C" void kernel_launch(void* const* d_in, const int* in_sizes, int n_in,
                              void* d_out, int out_size, void* d_ws, size_t ws_size,
                              hipStream_t stream) {
    const float* x     = (const float*)d_in[0];
    const int*   src   = (const int*)d_in[1];
    const int*   dst   = (const int*)d_in[2];
    const float* W1    = (const float*)d_in[3];
    const float* b1    = (const float*)d_in[4];
    const float* W2    = (const float*)d_in[5];
    const float* b2    = (const float*)d_in[6];
    const float* gamma = (const float*)d_in[7];
    const float* beta  = (const float*)d_in[8];
    const float* rmean = (const float*)d_in[9];
    const float* rvar  = (const float*)d_in[10];
    float* out = (float*)d_out;

    // ws layout
    float* buf1   = (float*)d_ws;                       // N*D f32 aggregator
    int*   deg    = (int*)(buf1 + (size_t)NN * D);      // 2N int
    float* norm   = (float*)(deg + 2 * NN);             // 2N f32
    int*   row    = (int*)(norm + 2 * NN);              // NN+1 int
    int*   cursor = row + NN + 1;                       // NN int
    int*   bsum   = cursor + NN;                        // NB int
    int*   boffs  = bsum + NB;                          // NB int
    int*   csr    = boffs + NB;                         // NE int
    float* norm_s = norm;
    float* norm_d = norm + NN;
    const int* deg_in = deg + NN;

    hipMemsetAsync(deg, 0, 2 * NN * sizeof(int), stream);
    deg_kernel<<<(NE + 255) / 256, 256, 0, stream>>>(src, dst, deg);
    norm_kernel<<<(NN + 255) / 256, 256, 0, stream>>>(deg, norm);

    // CSR by destination
    scan1_reduce<<<NB, 256, 0, stream>>>(deg_in, bsum);
    scan2_offsets<<<1, 64, 0, stream>>>(bsum, boffs);
    scan3_rowptr<<<NB, 256, 0, stream>>>(deg_in, boffs, row, cursor);
    scatter_kernel<<<(NE + 255) / 256, 256, 0, stream>>>(src, dst, cursor, csr);

    const int AGG_BLOCKS = (NN + 3) / 4;
    // layer 0: agg = selfloop + sum_e x[src]*ns[src]
    csr_agg<true><<<AGG_BLOCKS, 256, 0, stream>>>(row, csr, x, norm_s, buf1);
    gemm_kernel<true><<<512, 256, 0, stream>>>(buf1, W1, b1, norm_s, norm_d,
                                               gamma, beta, rmean, rvar, out);
    // layer 1: gather source = d_out (hs, norm_src already folded)
    csr_agg<false><<<AGG_BLOCKS, 256, 0, stream>>>(row, csr, out, nullptr, buf1);
    gemm_kernel<false><<<512, 256, 0, stream>>>(buf1, W2, b2, norm_s, norm_d,
                                                nullptr, nullptr, nullptr, nullptr, out);
}